// Round 1
// baseline (277.670 us; speedup 1.0000x reference)
//
#include <hip/hip_runtime.h>

#define HEADS 4
#define OUT_CH 16
#define CCH 64            // HEADS*OUT_CH
#define IN_CH 128
#define NEG_SLOPE 0.2f

// ---------------------------------------------------------------------------
// GEMM: h[N][64] = x[N][128] @ w[128][64]  (f32 vector ALU; no fp32 MFMA)
// One wave per row: lane = output channel. Weight staged in LDS (32 KB).
// ---------------------------------------------------------------------------
__global__ __launch_bounds__(256) void gat_gemm(const float* __restrict__ x,
                                                const float* __restrict__ w,
                                                float* __restrict__ h, int N) {
    __shared__ float wlds[IN_CH * CCH];
    int t = threadIdx.x;
    #pragma unroll
    for (int i = 0; i < (IN_CH * CCH) / 256; ++i)
        wlds[t + i * 256] = w[t + i * 256];
    __syncthreads();

    int lane = t & 63;
    int row = blockIdx.x * 4 + (t >> 6);
    if (row >= N) return;

    const float* xr = x + (long long)row * IN_CH;
    float acc = 0.f;
    #pragma unroll 8
    for (int k = 0; k < IN_CH; ++k)
        acc = fmaf(xr[k], wlds[k * CCH + lane], acc);
    h[(long long)row * CCH + lane] = acc;
}

// ---------------------------------------------------------------------------
// Init: out[n][c] = bias[c]  (deterministic accumulator base each call)
// ---------------------------------------------------------------------------
__global__ void gat_init(float* __restrict__ out, const float* __restrict__ bias,
                         long long total) {
    long long i = (long long)blockIdx.x * blockDim.x + threadIdx.x;
    if (i < total) out[i] = bias[i & 63];
}

// ---------------------------------------------------------------------------
// Edge kernel: one wave per edge. lane = channel (head = lane>>4).
//   alpha_h = leakyrelu( h[row]·att_i[h] + h[col]·att_j[h] )
//   w = softmax over 4 heads
//   out[col][c] += h[row][c] * w[head(c)]
// ---------------------------------------------------------------------------
__global__ __launch_bounds__(256) void gat_edge(const int* __restrict__ rows,
                                                const int* __restrict__ cols,
                                                const float* __restrict__ h,
                                                const float* __restrict__ att,
                                                float* __restrict__ out,
                                                int E, int N) {
    long long gid = (long long)blockIdx.x * blockDim.x + threadIdx.x;
    int e = (int)(gid >> 6);
    int total = E + N;
    if (e >= total) return;
    int lane = threadIdx.x & 63;

    int r, c;
    if (e < E) { r = rows[e]; c = cols[e]; }
    else       { r = e - E;   c = r; }

    int head = lane >> 4;
    int ch   = lane & 15;

    float xi = h[(long long)r * CCH + lane];
    float xj = h[(long long)c * CCH + lane];
    // att layout: (1, HEADS, 2*OUT_CH): [head][0:16]=att_i, [head][16:32]=att_j
    float ai = att[head * (2 * OUT_CH) + ch];
    float aj = att[head * (2 * OUT_CH) + OUT_CH + ch];

    float s = xi * ai + xj * aj;
    // reduce within each 16-lane head group (masks < 16 never cross groups)
    s += __shfl_xor(s, 1);
    s += __shfl_xor(s, 2);
    s += __shfl_xor(s, 4);
    s += __shfl_xor(s, 8);

    // leaky relu
    float a = s > 0.f ? s : NEG_SLOPE * s;

    // softmax across the 4 heads (lanes differing in bits 4,5)
    float m = fmaxf(a, __shfl_xor(a, 16));
    m = fmaxf(m, __shfl_xor(m, 32));
    float ex = __expf(a - m);
    float sum = ex + __shfl_xor(ex, 16);
    sum += __shfl_xor(sum, 32);
    float wgt = ex / sum;

    atomicAdd(&out[(long long)c * CCH + lane], xi * wgt);
}

extern "C" void kernel_launch(void* const* d_in, const int* in_sizes, int n_in,
                              void* d_out, int out_size, void* d_ws, size_t ws_size,
                              hipStream_t stream) {
    const float* x    = (const float*)d_in[0];
    const int*   ei   = (const int*)  d_in[1];
    const float* w    = (const float*)d_in[2];
    const float* att  = (const float*)d_in[3];
    const float* bias = (const float*)d_in[4];
    float* out = (float*)d_out;
    float* h   = (float*)d_ws;   // N*64 f32 = 12.8 MB

    int N = in_sizes[0] / IN_CH;
    int E = in_sizes[1] / 2;

    // 1) h = x @ W
    gat_gemm<<<(N + 3) / 4, 256, 0, stream>>>(x, w, h, N);

    // 2) out = bias (broadcast)
    long long total_out = (long long)N * CCH;
    gat_init<<<(unsigned)((total_out + 255) / 256), 256, 0, stream>>>(out, bias, total_out);

    // 3) edge scatter
    int total_e = E + N;
    long long threads = (long long)total_e * 64;
    gat_edge<<<(unsigned)((threads + 255) / 256), 256, 0, stream>>>(
        ei, ei + E, h, att, out, E, N);
}